// Round 11
// baseline (109.358 us; speedup 1.0000x reference)
//
#include <hip/hip_runtime.h>
#include <hip/hip_bf16.h>

#define N_NODES 8192
#define F_IN 256
#define F_OUT 128

#define SPLITK 4
#define KQ (N_NODES / SPLITK)   // 2048
#define BK 64
#define NT (KQ / BK)            // 32
#define ABYTES 16384            // A tile: 64 rows x 64 k x fp32

typedef __attribute__((ext_vector_type(4))) float f32x4;
typedef __attribute__((ext_vector_type(8))) short bf16x8;
typedef __attribute__((ext_vector_type(4))) unsigned int u32x4;

static __device__ __forceinline__ short bfr(float x) {
    __hip_bfloat16 h = __float2bfloat16(x);   // RNE
    union { __hip_bfloat16 h; short s; } u; u.h = h;
    return u.s;
}

static __device__ __forceinline__ void gload16(const void* g, void* l) {
    __builtin_amdgcn_global_load_lds(
        (const __attribute__((address_space(1))) unsigned int*)g,
        (__attribute__((address_space(3))) unsigned int*)l, 16, 0, 0);
}

// Kernel 1: support^T[f][n] = sum_k X[n][k] * W[k][f]   (fp32 accum -> bf16)
__global__ __launch_bounds__(256) void support_kernel(
        const float* __restrict__ X, const float* __restrict__ W,
        unsigned short* __restrict__ supT) {
    __shared__ float Xs[32][68];
    __shared__ float Ws[64][128];
    const int t = threadIdx.x;
    const int n0 = blockIdx.x * 32;
    const int tc = t & 31;
    const int tr = t >> 5;
    float acc[4][4];
    #pragma unroll
    for (int i = 0; i < 4; ++i)
        #pragma unroll
        for (int j = 0; j < 4; ++j) acc[i][j] = 0.f;

    for (int k0 = 0; k0 < F_IN; k0 += 64) {
        __syncthreads();
        {
            const int r = t >> 3, kc = (t & 7) * 8;
            const float* src = X + (size_t)(n0 + r) * F_IN + k0 + kc;
            f32x4 v0 = *(const f32x4*)src;
            f32x4 v1 = *(const f32x4*)(src + 4);
            *(f32x4*)&Xs[r][kc]     = v0;
            *(f32x4*)&Xs[r][kc + 4] = v1;
        }
        {
            const int col = t & 127, kb = t >> 7;
            #pragma unroll
            for (int i = 0; i < 32; ++i) {
                const int k = kb + i * 2;
                Ws[k][col] = W[(size_t)(k0 + k) * F_OUT + col];
            }
        }
        __syncthreads();
        #pragma unroll 8
        for (int k = 0; k < 64; ++k) {
            const f32x4 b = *(const f32x4*)&Ws[k][tc * 4];
            float a[4];
            #pragma unroll
            for (int i = 0; i < 4; ++i) a[i] = Xs[tr * 4 + i][k];
            #pragma unroll
            for (int i = 0; i < 4; ++i) {
                acc[i][0] += a[i] * b.x; acc[i][1] += a[i] * b.y;
                acc[i][2] += a[i] * b.z; acc[i][3] += a[i] * b.w;
            }
        }
    }
    #pragma unroll
    for (int j = 0; j < 4; ++j) {
        const int col = tc * 4 + j;
        #pragma unroll
        for (int i = 0; i < 4; ++i) {
            supT[(size_t)col * N_NODES + n0 + tr * 4 + i] =
                (unsigned short)bfr(acc[i][j]);
        }
    }
}

// Kernel 2: out += adj[:, hK] @ support[hK]  (+bias when h==0) via HW fp32
// atomics. BM=64, BK=64, split-K=4, grid 512 x 512 thr (8 waves 2Mx4N,
// wave = 32x32 out).
//   A (HBM): global_load_lds, 3 x 16KB buffers, staged 2 tiles ahead.
//   B (L2):  inline-asm global->VGPR, 2 named sets, staged 1 tile ahead.
// Manual FIFO ledger, 6 ops/body issued as [B(tt+1)x4, A(tt+2)x2]; fence =
// s_waitcnt vmcnt(2) + s_barrier: retires A(tt+1)+B(tt+1), keeps A(tt+2) in
// flight across the barrier. Steady state never drains the VMEM queue.
__global__ __launch_bounds__(512, 4) void gcn_kernel(
        const float* __restrict__ adj, const unsigned short* __restrict__ supT,
        const float* __restrict__ bias, float* __restrict__ out) {
    __shared__ char lds[3 * ABYTES];        // 48 KB -> 2 blocks/CU
    const int t = threadIdx.x;
    const int l = t & 63;
    const int w = t >> 6;                   // 0..7
    const int rb = blockIdx.x & 127;
    const int h = blockIdx.x >> 7;          // K-quarter
    const int n0 = rb * 64;
    const int k0 = h * KQ;

    // ---- A staging sources (per-lane, pre-swizzled; R6/R9-proven) ----
    const int rA0 = 8 * w + (l >> 4);
    const int rA1 = rA0 + 4;
    const char* gA0 = (const char*)adj
        + ((size_t)(n0 + rA0) * N_NODES + k0) * 4 + (((l & 15) ^ (rA0 & 15)) * 16);
    const char* gA1 = (const char*)adj
        + ((size_t)(n0 + rA1) * N_NODES + k0) * 4 + (((l & 15) ^ (rA1 & 15)) * 16);
    const int a_d0 = w * 2048;              // wave-uniform dest (HW adds lane*16)
    const int a_d1 = a_d0 + 1024;

    // ---- B register-load offsets (saddr form: SGPR base + 32-bit voffset) ----
    const int wm = w >> 2, wn = w & 3;
    const int f0 = wn * 32 + (l & 15);
    unsigned int boff0 = (unsigned)f0 * (N_NODES * 2) + (unsigned)(k0 * 2)
                       + ((l >> 4) * 16);
    unsigned int boff1 = boff0 + 16u * (N_NODES * 2);

    // ---- A read offsets ----
    const int aoff0 = (wm * 32 + (l & 15)) * 256;
    const int aoff1 = aoff0 + 16 * 256;
    const int akey = l & 15;
    const int ac0 = (l >> 4) * 2;

    f32x4 acc00 = {0.f,0.f,0.f,0.f}, acc01 = {0.f,0.f,0.f,0.f};
    f32x4 acc10 = {0.f,0.f,0.f,0.f}, acc11 = {0.f,0.f,0.f,0.f};

    // two named B sets: E (even tt), O (odd tt); frags: 0=(b0,ks0) 1=(b0,ks1)
    // 2=(b1,ks0) 3=(b1,ks1)
    u32x4 bE0, bE1, bE2, bE3;
    u32x4 bO0, bO1, bO2, bO3;

#define PK(dst, a, b) \
    asm("v_cvt_pk_bf16_f32 %0, %1, %2" : "=v"(dst) : "v"(a), "v"(b))

#define BLD(dst, off, imm) \
    asm volatile("global_load_dwordx4 %0, %1, %2 offset:" imm \
                 : "=v"(dst) : "v"(off), "s"(supT) : "memory")

#define STAGE_BREG(SET) { \
    BLD(b##SET##0, boff0, "0");  BLD(b##SET##1, boff0, "64"); \
    BLD(b##SET##2, boff1, "0");  BLD(b##SET##3, boff1, "64"); \
    boff0 += 128; boff1 += 128; }

#define STAGE_A(AI) { \
    char* bb = &lds[(AI) * ABYTES]; \
    gload16(gA0, bb + a_d0); \
    gload16(gA1, bb + a_d1); \
    gA0 += 256; gA1 += 256; }

#define FENCE(IMM) { \
    asm volatile("s_waitcnt vmcnt(" IMM ")" ::: "memory"); \
    __builtin_amdgcn_sched_barrier(0); \
    __builtin_amdgcn_s_barrier(); \
    __builtin_amdgcn_sched_barrier(0); }

#define HALF(ABUF, CA, BF0, BF1) { \
    f32x4 a0lo = *(const f32x4*)((ABUF) + aoff0 + ((((CA)    ) ^ akey) * 16)); \
    f32x4 a0hi = *(const f32x4*)((ABUF) + aoff0 + ((((CA) + 1) ^ akey) * 16)); \
    f32x4 a1lo = *(const f32x4*)((ABUF) + aoff1 + ((((CA)    ) ^ akey) * 16)); \
    f32x4 a1hi = *(const f32x4*)((ABUF) + aoff1 + ((((CA) + 1) ^ akey) * 16)); \
    u32x4 p0, p1; \
    PK(p0.x, a0lo.x, a0lo.y); PK(p0.y, a0lo.z, a0lo.w); \
    PK(p0.z, a0hi.x, a0hi.y); PK(p0.w, a0hi.z, a0hi.w); \
    PK(p1.x, a1lo.x, a1lo.y); PK(p1.y, a1lo.z, a1lo.w); \
    PK(p1.z, a1hi.x, a1hi.y); PK(p1.w, a1hi.z, a1hi.w); \
    bf16x8 am0 = __builtin_bit_cast(bf16x8, p0); \
    bf16x8 am1 = __builtin_bit_cast(bf16x8, p1); \
    acc00 = __builtin_amdgcn_mfma_f32_16x16x32_bf16(am0, __builtin_bit_cast(bf16x8, BF0), acc00, 0, 0, 0); \
    acc01 = __builtin_amdgcn_mfma_f32_16x16x32_bf16(am0, __builtin_bit_cast(bf16x8, BF1), acc01, 0, 0, 0); \
    acc10 = __builtin_amdgcn_mfma_f32_16x16x32_bf16(am1, __builtin_bit_cast(bf16x8, BF0), acc10, 0, 0, 0); \
    acc11 = __builtin_amdgcn_mfma_f32_16x16x32_bf16(am1, __builtin_bit_cast(bf16x8, BF1), acc11, 0, 0, 0); }

#define COMPUTE(AI, SET) { \
    const char* abuf = &lds[(AI) * ABYTES]; \
    HALF(abuf, ac0,     b##SET##0, b##SET##2); \
    HALF(abuf, ac0 + 8, b##SET##1, b##SET##3); }

    // prologue: B(0) regs, A(0)->buf0, A(1)->buf1; retire B(0)+A(0)
    STAGE_BREG(E);
    STAGE_A(0);
    STAGE_A(1);
    FENCE("2");

    int ai = 0;                             // tt % 3
    // main: bodies tt = 0..NT-3 (even/odd pairs), uniform vmcnt(2)
    for (int t2 = 0; t2 < NT - 2; t2 += 2) {
        // body tt = t2 (even): use E; stage B(tt+1)->O, A(tt+2)
        STAGE_BREG(O);
        { const int an = (ai >= 1) ? ai - 1 : 2; STAGE_A(an); }
        COMPUTE(ai, E);
        FENCE("2");
        ai = (ai == 2) ? 0 : ai + 1;
        // body tt = t2+1 (odd): use O; stage B(tt+1)->E, A(tt+2)
        STAGE_BREG(E);
        { const int an = (ai >= 1) ? ai - 1 : 2; STAGE_A(an); }
        COMPUTE(ai, O);
        FENCE("2");
        ai = (ai == 2) ? 0 : ai + 1;
    }
    // body NT-2 (even): stage B(NT-1) only; drain fully
    STAGE_BREG(O);
    COMPUTE(ai, E);
    FENCE("0");
    ai = (ai == 2) ? 0 : ai + 1;
    // body NT-1 (odd): compute only
    COMPUTE(ai, O);

#undef COMPUTE
#undef HALF
#undef FENCE
#undef STAGE_A
#undef STAGE_BREG
#undef BLD
#undef PK

    // epilogue: atomic-accumulate into zeroed out; h==0 adds bias once.
    const int col = wn * 32 + (l & 15);
    const int row0 = n0 + wm * 32 + (l >> 4) * 4;
    const float bv0 = (h == 0) ? bias[col]      : 0.0f;
    const float bv1 = (h == 0) ? bias[col + 16] : 0.0f;
    #pragma unroll
    for (int i = 0; i < 4; ++i) {
        float* o0 = out + (size_t)(row0 + i) * F_OUT + col;
        float* o1 = out + (size_t)(row0 + i + 16) * F_OUT + col;
        unsafeAtomicAdd(&o0[0],  acc00[i] + bv0);
        unsafeAtomicAdd(&o0[16], acc01[i] + bv1);
        unsafeAtomicAdd(&o1[0],  acc10[i] + bv0);
        unsafeAtomicAdd(&o1[16], acc11[i] + bv1);
    }
}

extern "C" void kernel_launch(void* const* d_in, const int* in_sizes, int n_in,
                              void* d_out, int out_size, void* d_ws, size_t ws_size,
                              hipStream_t stream) {
    const float* input  = (const float*)d_in[0];
    const float* adj    = (const float*)d_in[1];
    const float* weight = (const float*)d_in[2];
    const float* bias   = (const float*)d_in[3];
    float* out = (float*)d_out;
    unsigned short* supT = (unsigned short*)d_ws;           // 2 MiB

    hipMemsetAsync(d_out, 0, (size_t)out_size * sizeof(float), stream);
    support_kernel<<<N_NODES / 32, 256, 0, stream>>>(input, weight, supT);
    gcn_kernel<<<128 * SPLITK, 512, 0, stream>>>(adj, supT, bias, out);
}

// Round 13
// 79.873 us; speedup vs baseline: 1.3691x; 1.3691x over previous
//
#include <hip/hip_runtime.h>
#include <hip/hip_bf16.h>

#define N_NODES 8192
#define F_IN 256
#define F_OUT 128

#define SPLITK 4
#define KQ (N_NODES / SPLITK)   // 2048
#define BK 64
#define NT (KQ / BK)            // 32
#define A_LDS 8192              // A tile: 64 rows x 64 k x bf16 (128 B/row)
#define B_LDS 16384             // B tile: 128 f x 64 k x bf16
#define B_BASE (2 * A_LDS)      // 16 KB
#define LDS_TOTAL (2 * A_LDS + 2 * B_LDS)   // 48 KB -> 2 blocks/CU

typedef __attribute__((ext_vector_type(4))) float f32x4;
typedef __attribute__((ext_vector_type(8))) short bf16x8;
typedef __attribute__((ext_vector_type(4))) unsigned int u32x4;

static __device__ __forceinline__ short bfr(float x) {
    __hip_bfloat16 h = __float2bfloat16(x);   // RNE
    union { __hip_bfloat16 h; short s; } u; u.h = h;
    return u.s;
}

static __device__ __forceinline__ void gload16(const void* g, void* l) {
    __builtin_amdgcn_global_load_lds(
        (const __attribute__((address_space(1))) unsigned int*)g,
        (__attribute__((address_space(3))) unsigned int*)l, 16, 0, 0);
}

// Kernel 1: support^T[f][n] = sum_k X[n][k] * W[k][f]   (fp32 accum -> bf16)
__global__ __launch_bounds__(256) void support_kernel(
        const float* __restrict__ X, const float* __restrict__ W,
        unsigned short* __restrict__ supT) {
    __shared__ float Xs[32][68];
    __shared__ float Ws[64][128];
    const int t = threadIdx.x;
    const int n0 = blockIdx.x * 32;
    const int tc = t & 31;
    const int tr = t >> 5;
    float acc[4][4];
    #pragma unroll
    for (int i = 0; i < 4; ++i)
        #pragma unroll
        for (int j = 0; j < 4; ++j) acc[i][j] = 0.f;

    for (int k0 = 0; k0 < F_IN; k0 += 64) {
        __syncthreads();
        {
            const int r = t >> 3, kc = (t & 7) * 8;
            const float* src = X + (size_t)(n0 + r) * F_IN + k0 + kc;
            f32x4 v0 = *(const f32x4*)src;
            f32x4 v1 = *(const f32x4*)(src + 4);
            *(f32x4*)&Xs[r][kc]     = v0;
            *(f32x4*)&Xs[r][kc + 4] = v1;
        }
        {
            const int col = t & 127, kb = t >> 7;
            #pragma unroll
            for (int i = 0; i < 32; ++i) {
                const int k = kb + i * 2;
                Ws[k][col] = W[(size_t)(k0 + k) * F_OUT + col];
            }
        }
        __syncthreads();
        #pragma unroll 8
        for (int k = 0; k < 64; ++k) {
            const f32x4 b = *(const f32x4*)&Ws[k][tc * 4];
            float a[4];
            #pragma unroll
            for (int i = 0; i < 4; ++i) a[i] = Xs[tr * 4 + i][k];
            #pragma unroll
            for (int i = 0; i < 4; ++i) {
                acc[i][0] += a[i] * b.x; acc[i][1] += a[i] * b.y;
                acc[i][2] += a[i] * b.z; acc[i][3] += a[i] * b.w;
            }
        }
    }
    #pragma unroll
    for (int j = 0; j < 4; ++j) {
        const int col = tc * 4 + j;
        #pragma unroll
        for (int i = 0; i < 4; ++i) {
            supT[(size_t)col * N_NODES + n0 + tr * 4 + i] =
                (unsigned short)bfr(acc[i][j]);
        }
    }
}

// Kernel 2: out += adj[:, hK] @ support[hK]  (+bias when h==0) via HW fp32
// atomics. BM=64, BK=64, split-K=4, grid 512 x 512 thr (8 waves 2Mx4N,
// wave = 32x32 out). 48 KB LDS -> 2 blocks/CU.
//   A (HBM): reg-staged depth-2 — asm global loads tile tt+2 -> 8 fp32 regs;
//            cvt_pk -> bf16 -> swizzled ds_write_b128 into 2x8KB A-buffers.
//   B (L2):  global_load_lds depth-1 into 2x16KB buffers (R9-proven).
// Ledger (issue order B(tt+1)x2, A(tt+2)x2): mid-body vmcnt(4) -> A(tt+1)
// regs ready for cvt; end fence vmcnt(2)+lgkmcnt(0) -> B(tt+1)+ds_write done,
// A(tt+2) rides across the barrier (2-body slack). Compute phase: 8 bf16
// ds_read_b128 + 8 MFMA, zero cvt.
__global__ __launch_bounds__(512, 4) void gcn_kernel(
        const float* __restrict__ adj, const unsigned short* __restrict__ supT,
        const float* __restrict__ bias, float* __restrict__ out) {
    __shared__ char lds[LDS_TOTAL];
    const int t = threadIdx.x;
    const int l = t & 63;
    const int w = t >> 6;                   // 0..7
    const int rb = blockIdx.x & 127;
    const int h = blockIdx.x >> 7;          // K-quarter
    const int n0 = rb * 64;
    const int k0 = h * KQ;

    // ---- A reg-stage source: lane l -> row 8w+(l>>3), 8 floats at (l&7)*8
    const int arow = 8 * w + (l >> 3);
    unsigned int aoffv = (unsigned)(((size_t)(n0 + arow) * N_NODES + k0
                                     + (l & 7) * 8) * 4);
    // A ds_write addr (swizzled): chunk c=l&7, key=row&7=(l>>3)&7
    const int awoff = arow * 128 + (((l & 7) ^ ((l >> 3) & 7)) * 16);

    // ---- B staging (gload_lds, pre-swizzled source; R9-proven) ----
    const char* gB0 = (const char*)supT
        + ((size_t)(16 * w + (l >> 3)) * N_NODES + k0) * 2 + (((l & 7) ^ (l >> 3)) * 16);
    const char* gB1 = gB0 + (size_t)8 * N_NODES * 2;
    const int b_d0 = w * 2048;              // wave-uniform dest (HW adds lane*16)
    const int b_d1 = b_d0 + 1024;

    // ---- read-side offsets ----
    const int wm = w >> 2, wn = w & 3;
    const int aoff0 = (wm * 32 + (l & 15)) * 128;    // A row ar0 (bf16)
    const int aoff1 = aoff0 + 16 * 128;              // ar0+16 (same key)
    const int akey = l & 7;                          // row&7
    const int boff0 = (wn * 32 + (l & 15)) * 128;
    const int boff1 = boff0 + 16 * 128;
    const int bkey = l & 7;                          // f&7
    const int cg = l >> 4;                           // k-chunk group 0..3

    f32x4 acc00 = {0.f,0.f,0.f,0.f}, acc01 = {0.f,0.f,0.f,0.f};
    f32x4 acc10 = {0.f,0.f,0.f,0.f}, acc11 = {0.f,0.f,0.f,0.f};

    // 2 named A-raw reg sets (8 floats each), parity = tile & 1
    f32x4 aE0, aE1, aO0, aO1;

#define PK(dst, a, b) \
    asm("v_cvt_pk_bf16_f32 %0, %1, %2" : "=v"(dst) : "v"(a), "v"(b))

#define BLDA(dst, imm) \
    asm volatile("global_load_dwordx4 %0, %1, %2 offset:" imm \
                 : "=v"(dst) : "v"(aoffv), "s"(adj) : "memory")

#define STAGE_AREG(r0, r1) { \
    BLDA(r0, "0"); \
    BLDA(r1, "16"); \
    aoffv += 256; }

#define STAGE_B(P) { \
    char* bb = &lds[B_BASE + (P) * B_LDS]; \
    gload16(gB0, bb + b_d0); \
    gload16(gB1, bb + b_d1); \
    gB0 += 128; gB1 += 128; }

#define CVT_WRITE(WP, r0, r1) { \
    u32x4 q; \
    PK(q.x, r0.x, r0.y); PK(q.y, r0.z, r0.w); \
    PK(q.z, r1.x, r1.y); PK(q.w, r1.z, r1.w); \
    *(u32x4*)(&lds[(WP) * A_LDS] + awoff) = q; }

#define COMPUTE(P) { \
    const char* ab = &lds[(P) * A_LDS]; \
    const char* bb = &lds[B_BASE + (P) * B_LDS]; \
    _Pragma("unroll") \
    for (int ks = 0; ks < 2; ++ks) { \
        const int c = ks * 4 + cg; \
        bf16x8 a0 = *(const bf16x8*)(ab + aoff0 + ((c ^ akey) * 16)); \
        bf16x8 a1 = *(const bf16x8*)(ab + aoff1 + ((c ^ akey) * 16)); \
        bf16x8 b0 = *(const bf16x8*)(bb + boff0 + ((c ^ bkey) * 16)); \
        bf16x8 b1 = *(const bf16x8*)(bb + boff1 + ((c ^ bkey) * 16)); \
        acc00 = __builtin_amdgcn_mfma_f32_16x16x32_bf16(a0, b0, acc00, 0, 0, 0); \
        acc01 = __builtin_amdgcn_mfma_f32_16x16x32_bf16(a0, b1, acc01, 0, 0, 0); \
        acc10 = __builtin_amdgcn_mfma_f32_16x16x32_bf16(a1, b0, acc10, 0, 0, 0); \
        acc11 = __builtin_amdgcn_mfma_f32_16x16x32_bf16(a1, b1, acc11, 0, 0, 0); \
    } }

#define WAIT(IMM) { \
    asm volatile("s_waitcnt vmcnt(" IMM ")" ::: "memory"); \
    __builtin_amdgcn_sched_barrier(0); }

#define WAITL(IMM) { \
    asm volatile("s_waitcnt vmcnt(" IMM ") lgkmcnt(0)" ::: "memory"); \
    __builtin_amdgcn_sched_barrier(0); }

#define BAR() { \
    __builtin_amdgcn_s_barrier(); \
    __builtin_amdgcn_sched_barrier(0); }

    // prologue: queue = [A0(E)x2] -> +B(0)x2 -> +A1(O)x2
    STAGE_AREG(aE0, aE1);   // tile 0
    STAGE_B(0);             // tile 0
    STAGE_AREG(aO0, aO1);   // tile 1
    WAIT("4");              // retire A0 regs
    CVT_WRITE(0, aE0, aE1); // tile 0 -> A-buf0
    WAITL("2");             // retire B(0) + own ds_write; A1 rides
    BAR();

    // full bodies tt = 0..NT-3 (30 bodies, even/odd pairs)
    for (int t2 = 0; t2 + 3 < NT; t2 += 2) {
        // body tt even (p=0): cvt O (tile tt+1), load E (tile tt+2)
        STAGE_B(1);
        STAGE_AREG(aE0, aE1);
        COMPUTE(0);
        WAIT("4");
        CVT_WRITE(1, aO0, aO1);
        WAITL("2");
        BAR();
        // body tt odd (p=1): cvt E (tile tt+2... parity: tile tt+1 is even->E), load O
        STAGE_B(0);
        STAGE_AREG(aO0, aO1);
        COMPUTE(1);
        WAIT("4");
        CVT_WRITE(0, aE0, aE1);
        WAITL("2");
        BAR();
    }
    // body NT-2 (even p=0): stage B(NT-1) only; cvt O (tile NT-1)
    STAGE_B(1);
    COMPUTE(0);
    WAIT("2");              // queue [A(NT-1)x2, B(NT-1)x2] -> retire A regs
    CVT_WRITE(1, aO0, aO1);
    WAITL("0");
    BAR();
    // body NT-1 (p=1): compute only
    COMPUTE(1);

#undef PK
#undef BLDA
#undef STAGE_AREG
#undef STAGE_B
#undef CVT_WRITE
#undef COMPUTE
#undef WAIT
#undef WAITL
#undef BAR

    // epilogue: atomic-accumulate into zeroed out; h==0 adds bias once.
    const int col = wn * 32 + (l & 15);
    const int row0 = n0 + wm * 32 + (l >> 4) * 4;
    const float bv0 = (h == 0) ? bias[col]      : 0.0f;
    const float bv1 = (h == 0) ? bias[col + 16] : 0.0f;
    #pragma unroll
    for (int i = 0; i < 4; ++i) {
        float* o0 = out + (size_t)(row0 + i) * F_OUT + col;
        float* o1 = out + (size_t)(row0 + i + 16) * F_OUT + col;
        unsafeAtomicAdd(&o0[0],  acc00[i] + bv0);
        unsafeAtomicAdd(&o0[16], acc01[i] + bv1);
        unsafeAtomicAdd(&o1[0],  acc10[i] + bv0);
        unsafeAtomicAdd(&o1[16], acc11[i] + bv1);
    }
}

extern "C" void kernel_launch(void* const* d_in, const int* in_sizes, int n_in,
                              void* d_out, int out_size, void* d_ws, size_t ws_size,
                              hipStream_t stream) {
    const float* input  = (const float*)d_in[0];
    const float* adj    = (const float*)d_in[1];
    const float* weight = (const float*)d_in[2];
    const float* bias   = (const float*)d_in[3];
    float* out = (float*)d_out;
    unsigned short* supT = (unsigned short*)d_ws;           // 2 MiB

    hipMemsetAsync(d_out, 0, (size_t)out_size * sizeof(float), stream);
    support_kernel<<<N_NODES / 32, 256, 0, stream>>>(input, weight, supT);
    gcn_kernel<<<128 * SPLITK, 512, 0, stream>>>(adj, supT, bias, out);
}